// Round 10
// baseline (136.288 us; speedup 1.0000x reference)
//
#include <hip/hip_runtime.h>

#define RR 4096
#define AA 101
#define PAD_W 104
#define KK 32
#define NAG 4000000

#define NCHUNK 32
#define DR 512
#define NRANGE 8
#define EPB (RR * KK / NCHUNK)   // 4096 edges per chunk
#define NB 512                   // hist blocks
#define NMIG (NRANGE * NCHUNK)   // 256 migrate blocks

static constexpr float EPS  = 1e-9f;
static constexpr float DT   = 1.0f / 365.0f;
static constexpr float FRAC_MOVE = 0.02f / 365.0f;

static constexpr float SC2   = 4.0f;             // wallet quantum 0.25
static constexpr float INV2  = 0.25f;
static constexpr float SC9   = 512.0f;           // greed quantum 2^-9
static constexpr float INV9  = 1.0f / 512.0f;
static constexpr float SC18  = 262144.0f;        // 2^18 (migrate)
static constexpr float INV18 = 1.0f / 262144.0f;

// ---------------- d_out offsets (f32 elements, return order) ----------------
#define OUT_POP   0
#define OUT_POPN  413696
#define OUT_GDP   417792
#define OUT_DEV   421888
#define OUT_H     425984
#define OUT_CONS  430080
#define OUT_LAB   434176
#define OUT_PSR   438272
#define OUT_DEP   442368
#define OUT_ATP   446464
#define OUT_ADP   4446464
#define OUT_AMP   8446464
#define OUT_PATP  12446464
#define OUT_PADP  12450560
#define OUT_PAMP  12454656

static __device__ __forceinline__ float clampf(float x, float lo, float hi) {
    return fminf(fmaxf(x, lo), hi);
}
static __device__ __forceinline__ float wred(float x) {
#pragma unroll
    for (int m = 32; m; m >>= 1) x += __shfl_xor(x, m);
    return x;
}

// ---------------- kernel 1: per-region stage 1, wave-per-region ----------------
__global__ __launch_bounds__(256) void k_region1(
    const float* __restrict__ aec, const float* __restrict__ gdp_pc,
    const float* __restrict__ gdp_ema_in, const float* __restrict__ gdp_base,
    const float* __restrict__ dev_in, const float* __restrict__ sink_use,
    const float* __restrict__ sink_cap, const float* __restrict__ haz_base,
    const float* __restrict__ pop_age, const float* __restrict__ population,
    const float* __restrict__ aging, const float* __restrict__ asfr,
    const float* __restrict__ distance, const int* __restrict__ nbr,
    float* __restrict__ Wpa, float* __restrict__ Wdfrac, float* __restrict__ Wbsurv,
    float* __restrict__ Wattr, float* __restrict__ Wgdist, float* __restrict__ Wdsum,
    float* __restrict__ O)
{
    int wid = threadIdx.x >> 6, lane = threadIdx.x & 63;
    int r = blockIdx.x * 4 + wid;

    float aec_norm = clampf(aec[r], 0.0f, 1.0f);
    float gprev = gdp_ema_in[r];
    float gema  = gprev * 0.9f + 0.1f * gdp_pc[r];
    float base  = gdp_base[r];
    float g_ratio = logf(fmaxf(gema / (base + EPS), 1e-6f));
    float g_term  = clampf(0.5f + 0.5f * tanhf(0.5f * g_ratio), 0.0f, 1.0f);
    float util = clampf(sink_use[r] / (sink_cap[r] + EPS), 0.0f, 1.0f);
    float H = clampf(0.5f * aec_norm + 0.4f * g_term + 0.1f * (1.0f - util), 0.0f, 1.0f);
    float dev_proxy = clampf(0.5f + 0.5f * tanhf(0.3f * g_ratio), 0.0f, 1.0f);
    float dev = dev_in[r] * 0.99f + 0.01f * dev_proxy;

    float m_neon  = expf(-2.0f * H);
    float m_child = expf(-1.5f * H);
    float m_adult = expf(-1.0f * H);
    float hazmul = 1.0f + 0.5f * util;

    int a0 = lane * 2, a1 = a0 + 1;
    bool v0 = (a0 < AA), v1 = (a1 < AA);

    float p0 = 0.f, p1 = 0.f, hz0 = 0.f, hz1 = 0.f;
    if (v0) {
        p0 = pop_age[r * AA + a0];
        float mult = (a0 == 0) ? m_neon : ((a0 < 15) ? m_child : m_adult);
        hz0 = clampf(haz_base[a0] * mult * hazmul, 0.0f, 5.0f);
    }
    if (v1) {
        p1 = pop_age[r * AA + a1];
        float mult = (a1 < 15) ? m_child : m_adult;
        hz1 = clampf(haz_base[a1] * mult * hazmul, 0.0f, 5.0f);
    }
    float s0 = v0 ? p0 * expf(-hz0 * DT) : 0.f;
    float s1 = v1 ? p1 * expf(-hz1 * DT) : 0.f;
    float sp = __shfl_up(s1, 1);   // s[a0-1]

    float Md0 = 0.f, Md1 = 0.f, Ms0 = 0.f, Ms1 = 0.f;
    if (v0) { Md0 = aging[a0 * AA + a0]; if (a0 > 0) Ms0 = aging[(a0 - 1) * AA + a0]; }
    if (v1) { Md1 = aging[a1 * AA + a1]; Ms1 = aging[(a1 - 1) * AA + a1]; }

    float pa0 = v0 ? ((a0 == 0) ? s0 * Md0 : s0 * Md0 + sp * Ms0) : 0.f;
    float pa1 = v1 ? (s1 * Md1 + s0 * Ms1) : 0.f;

    if (v0 && a0 > 0) Wpa[r * PAD_W + a0] = pa0;
    if (v1)           Wpa[r * PAD_W + a1] = pa1;

    float pop_sum  = wred(p0 + p1);
    float surv_sum = wred(s0 + s1);
    float haz05 = wred(((v0 && a0 < 5) ? hz0 : 0.f) + ((v1 && a1 < 5) ? hz1 : 0.f));
    float bs0 = (a0 >= 15 && a0 < 50) ? 0.5f * pa0 * asfr[a0 - 15] : 0.f;
    float bs1 = (a1 >= 15 && a1 < 50) ? 0.5f * pa1 * asfr[a1 - 15] : 0.f;
    float b_sum = wred(bs0 + bs1);

    float dc = 0.f;
    if (lane < KK) {
        int idx = nbr[r * KK + lane];
        float d = distance[(size_t)r * RR + idx];
        Wgdist[r * KK + lane] = d;
        dc = d;
    }
    float dsum = wred(dc);

    if (lane == 0) {
        O[OUT_GDP + r] = gema;
        O[OUT_DEV + r] = dev;
        O[OUT_H + r]   = H;

        float deaths = fmaxf(pop_sum - surv_sum, 0.0f);
        Wdfrac[r] = clampf(deaths / (population[r] + EPS), 0.0f, 0.99f);

        float surv_u5 = expf(-haz05);
        float F_dev = clampf(expf(-dev), 0.5f, 1.5f);
        float F_rep = clampf(0.995f / fmaxf(surv_u5, 0.001f), 0.5f, 1.8f);
        float g_growth = logf(fmaxf(gema + EPS, 1e-6f)) - logf(fmaxf(gprev + EPS, 1e-6f));
        float F_cyc = clampf(expf(-5.0f * fmaxf(-g_growth, 0.0f)), 0.6f, 1.2f);
        float F_total = clampf(F_dev * F_rep * F_cyc, 0.4f, 1.8f);
        float births = fmaxf(b_sum * F_total * DT, 0.0f);
        float bsurv = births * expf(-hz0 * DT);       // hz0 on lane0 = haz[0]
        Wbsurv[r] = bsurv;
        Wpa[r * PAD_W + 0] = pa0 + bsurv;             // lane0 pa0 = pa(age 0)

        Wattr[r] = 0.6f * (gdp_pc[r] / (base + EPS)) + 0.4f * (0.5f + 0.5f * aec_norm);
        Wdsum[r] = dsum;
    }
}

// ---------------- kernel 2a: migration weights + outflow (means inlined) ----------------
__global__ __launch_bounds__(256) void k_migrate_a(
    const int* __restrict__ nbr, const float* __restrict__ Wattr,
    const float* __restrict__ Wgdist, const float* __restrict__ Wdsum,
    float* __restrict__ Wpa, float* __restrict__ Wash, float* __restrict__ Wmove)
{
    __shared__ float sred[8];
    int t = threadIdx.x;
    {
        float a = 0.f, d = 0.f;
        for (int i = t; i < RR; i += 256) { a += Wattr[i]; d += Wdsum[i]; }
        a = wred(a); d = wred(d);
        int w0 = t >> 6;
        if ((t & 63) == 0) { sred[w0] = a; sred[4 + w0] = d; }
    }
    __syncthreads();
    float asum = sred[0] + sred[1] + sred[2] + sred[3];
    float dall = sred[4] + sred[5] + sred[6] + sred[7];
    float inv_am = 1.0f / (asum / (float)RR + EPS);
    float inv_dm = 1.0f / (dall / (float)(RR * KK) + EPS);

    int wid = t >> 6, lane = t & 63;
    int r = blockIdx.x * 4 + wid;

    float mob = 0.f;
    if (lane < 22) mob = Wpa[r * PAD_W + 18 + lane];
    float msum = wred(lane < 22 ? mob : 0.f);

    float w = 0.f;
    if (lane < KK) {
        int idx = nbr[r * KK + lane];
        float an = Wattr[idx] * inv_am;
        float cost = 1.0f + Wgdist[r * KK + lane] * inv_dm;
        w = fmaxf(an / cost, 0.0f);
    }
    float wsum = wred(lane < KK ? w : 0.f);

    float out_R = msum * FRAC_MOVE;
    float invw = 1.0f / (wsum + EPS);
    float move_sum = out_R * wsum * invw;
    float inv_ms = 1.0f / (msum + EPS);

    if (lane < 22) {
        float ash = mob * inv_ms;
        Wash[r * 22 + lane] = ash;
        Wpa[r * PAD_W + 18 + lane] = mob - ash * move_sum;
    }
    if (lane < KK) Wmove[r * KK + lane] = out_R * w * invw;
}

// ---------------- kernel 3: FUSED inflow scatter + agent segment sums ----------------
// blocks [0, NMIG):          migrate inflow -> Smig (u64-packed LDS, 45KB)
// blocks [NMIG, NMIG+NB):    agent hist -> S (one u64 atomic per agent, 32KB of same buffer)
__global__ __launch_bounds__(512) void k_migbhist(
    const int* __restrict__ nbr, const float* __restrict__ Wash,
    const float* __restrict__ Wmove, float* __restrict__ Smig,
    const int* __restrict__ reg, const float* __restrict__ greed,
    const float* __restrict__ atp, const float* __restrict__ adp,
    const float* __restrict__ amp, unsigned long long* __restrict__ S)
{
    __shared__ unsigned long long h[11 * DR];   // 45056 B (hist uses first RR=4096)
    int bid = blockIdx.x;

    if (bid < NMIG) {
        int range = bid & (NRANGE - 1);
        int chunk = bid >> 3;
        int d0 = range * DR;

        for (int i = threadIdx.x; i < 11 * DR; i += 512) h[i] = 0ull;
        __syncthreads();

        int tend = (chunk + 1) * EPB;
        for (int t = chunk * EPB + threadIdx.x; t < tend; t += 512) {
            int idx = nbr[t];
            if (idx >= d0 && idx < d0 + DR) {
                int rsrc = t >> 5;
                float mv = Wmove[t];
                const float* ash = &Wash[rsrc * 22];
                int dl = idx - d0;
#pragma unroll
                for (int f = 0; f < 11; f++) {
                    unsigned long long lo = __float2uint_rn(ash[2 * f] * mv * SC18);
                    unsigned long long hi = __float2uint_rn(ash[2 * f + 1] * mv * SC18);
                    atomicAdd(&h[f * DR + dl], lo | (hi << 32));
                }
            }
        }
        __syncthreads();

        for (int i = threadIdx.x; i < 11 * DR; i += 512) {
            int f = i / DR, d = i - f * DR;
            unsigned long long v = h[i];
            Smig[(chunk * 22 + 2 * f) * RR + d0 + d]     = (float)(unsigned int)v * INV18;
            Smig[(chunk * 22 + 2 * f + 1) * RR + d0 + d] = (float)(v >> 32) * INV18;
        }
    } else {
        int b = bid - NMIG;
        for (int i = threadIdx.x; i < RR; i += 512) h[i] = 0ull;
        __syncthreads();

        const int4*   reg4 = (const int4*)reg;
        const float4* g4 = (const float4*)greed;
        const float4* a4 = (const float4*)atp;
        const float4* d4 = (const float4*)adp;
        const float4* m4 = (const float4*)amp;
        const int NQ = NAG / 4;
        const int STRIDE = NB * 512;

        for (int q = b * 512 + threadIdx.x; q < NQ; q += STRIDE) {
            int4 rr = reg4[q];
            float4 gv = g4[q], av = a4[q], dv = d4[q], mv = m4[q];
#define DO1(RX, GX, AX, DX, MX) { \
            unsigned long long ai = __float2uint_rn((AX) * SC2); \
            unsigned long long di = __float2uint_rn((DX) * SC2); \
            unsigned long long mi = __float2uint_rn((MX) * SC2); \
            unsigned long long gi = __float2uint_rn(((GX) + 1e-9f) * SC9); \
            atomicAdd(&h[RX], ai | (di << 14) | (mi << 28) | (gi << 42) | (1ull << 56)); }
            DO1(rr.x, gv.x, av.x, dv.x, mv.x)
            DO1(rr.y, gv.y, av.y, dv.y, mv.y)
            DO1(rr.z, gv.z, av.z, dv.z, mv.z)
            DO1(rr.w, gv.w, av.w, dv.w, mv.w)
#undef DO1
        }
        __syncthreads();

        for (int i = threadIdx.x; i < RR; i += 512)
            S[(size_t)b * RR + i] = h[i];
    }
}

// ---------------- kernel 4: fold Smig -> Wadd (coalesced) ----------------
__global__ __launch_bounds__(256) void k_reduce(
    const float* __restrict__ Smig, float* __restrict__ Wadd)
{
    int t2 = blockIdx.x * 256 + threadIdx.x;   // < 22*4096
    int f = t2 >> 12, rr = t2 & (RR - 1);
    float acc = 0.f;
#pragma unroll
    for (int c = 0; c < NCHUNK; c++)
        acc += Smig[(c * 22 + f) * RR + rr];
    Wadd[rr * 24 + f] = acc;
}

// ---------------- kernel 5: finalize population (wave/region) + region2-from-S ----------------
__global__ __launch_bounds__(256) void k_fin(
    const float* __restrict__ Wpa, const float* __restrict__ Wadd,
    const float* __restrict__ cw, const float* __restrict__ pw,
    const float* __restrict__ cbase, const float* __restrict__ lbase,
    const unsigned long long* __restrict__ S,
    const float* __restrict__ Wdfrac, const float* __restrict__ Wbsurv,
    const float* __restrict__ patp, const float* __restrict__ padp,
    const float* __restrict__ pamp,
    float4* __restrict__ P4, float2* __restrict__ P2,
    float* __restrict__ O)
{
    int blk = blockIdx.x;
    if (blk < 1024) {
        int wid = threadIdx.x >> 6, lane = threadIdx.x & 63;
        int r = blk * 4 + wid;
        int a0 = lane * 2, a1 = a0 + 1;
        bool v0 = (a0 < AA), v1 = (a1 < AA);

        float va = 0.f, vb = 0.f;
        if (lane < 51) {
            float2 pp = *(const float2*)&Wpa[r * PAD_W + a0];
            va = pp.x; vb = pp.y;
        }
        if (a0 >= 18 && a0 < 40) {
            float2 ad = *(const float2*)&Wadd[r * 24 + (a0 - 18)];
            va += ad.x; vb += ad.y;
        }
        va = v0 ? fmaxf(va, 0.0f) : 0.f;
        vb = v1 ? fmaxf(vb, 0.0f) : 0.f;
        if (v0) O[OUT_POP + r * AA + a0] = va;
        if (v1) O[OUT_POP + r * AA + a1] = vb;

        float cw0 = v0 ? cw[a0] : 0.f, cw1 = v1 ? cw[a1] : 0.f;
        float pw0 = v0 ? pw[a0] : 0.f, pw1 = v1 ? pw[a1] : 0.f;

        float psum  = wred(va + vb);
        float cdot  = wred(va * cw0 + vb * cw1);
        float ldot  = wred(va * pw0 + vb * pw1);
        float young = wred(((a0 < 15) ? va : 0.f) + ((a1 < 15) ? vb : 0.f));
        float work  = wred(((a0 >= 15 && a0 < 65) ? va : 0.f) + ((a1 >= 15 && a1 < 65) ? vb : 0.f));
        float old   = wred(((a0 >= 65) ? va : 0.f) + ((a1 >= 65) ? vb : 0.f));

        if (lane == 0) {
            O[OUT_POPN + r] = fmaxf(psum, 0.0f);
            O[OUT_CONS + r] = clampf(cdot / (cbase[r] + EPS), 0.25f, 4.0f);
            O[OUT_LAB + r]  = clampf(ldot / (lbase[r] + EPS), 0.2f, 1.2f);
            O[OUT_PSR + r]  = work / (old + EPS);
            O[OUT_DEP + r]  = (young + old) / (work + EPS);
        }
    } else {
        int r = (blk - 1024) * 256 + threadIdx.x;
        if (r >= RR) return;
        float sa = 0.f, sd = 0.f, sm = 0.f, sg = 0.f, sc = 0.f;
#pragma unroll 4
        for (int b = 0; b < NB; b++) {
            unsigned long long p = S[(size_t)b * RR + r];
            sa += (float)(unsigned int)(p & 0x3FFFull);
            sd += (float)(unsigned int)((p >> 14) & 0x3FFFull);
            sm += (float)(unsigned int)((p >> 28) & 0x3FFFull);
            sg += (float)(unsigned int)((p >> 42) & 0x3FFFull);
            sc += (float)(unsigned int)(p >> 56);
        }
        sa *= INV2; sd *= INV2; sm *= INV2; sg *= INV9;

        float dfi = Wdfrac[r];
        float ra = sa * dfi;
        float rd = sd * dfi;
        float rm = sm * dfi;
        O[OUT_PATP + r] = patp[r] - ra * 0.2f;
        O[OUT_PADP + r] = padp[r] - rd * 0.2f;
        O[OUT_PAMP + r] = pamp[r] - rm * 0.2f;
        P4[r] = make_float4(1.0f - dfi, 1.0f / (sg + EPS), ra * 0.8f, rd * 0.8f);
        P2[r] = make_float2(rm * 0.8f, Wbsurv[r] / fmaxf(sc, 1.0f));
    }
}

// ---------------- kernel 6: agent apply, float4 ----------------
__global__ __launch_bounds__(256) void k_apply(
    const int* __restrict__ reg, const float* __restrict__ greed,
    const float* __restrict__ atp, const float* __restrict__ adp,
    const float* __restrict__ amp,
    const float4* __restrict__ P4, const float2* __restrict__ P2,
    float* __restrict__ O)
{
    int q = blockIdx.x * 256 + threadIdx.x;
    if (q >= NAG / 4) return;
    int4 rr = ((const int4*)reg)[q];
    float4 g = ((const float4*)greed)[q];
    float4 a = ((const float4*)atp)[q];
    float4 d = ((const float4*)adp)[q];
    float4 m = ((const float4*)amp)[q];
    float4 oa, od, om;
#define ONE(c) { float4 t4 = P4[rr.c]; float2 t2 = P2[rr.c]; \
    float wn = (g.c + 1e-9f) * t4.y; \
    oa.c = a.c * t4.x + wn * t4.z + t2.y; \
    od.c = d.c * t4.x + wn * t4.w; \
    om.c = m.c * t4.x + wn * t2.x; }
    ONE(x) ONE(y) ONE(z) ONE(w)
#undef ONE
    ((float4*)(O + OUT_ATP))[q] = oa;
    ((float4*)(O + OUT_ADP))[q] = od;
    ((float4*)(O + OUT_AMP))[q] = om;
}

extern "C" void kernel_launch(void* const* d_in, const int* in_sizes, int n_in,
                              void* d_out, int out_size, void* d_ws, size_t ws_size,
                              hipStream_t stream) {
    const float* aec       = (const float*)d_in[0];
    const float* gdp_pc    = (const float*)d_in[1];
    const float* gdp_ema   = (const float*)d_in[2];
    const float* gdp_base  = (const float*)d_in[3];
    const float* dev_in    = (const float*)d_in[4];
    const float* sink_use  = (const float*)d_in[5];
    const float* sink_cap  = (const float*)d_in[6];
    const float* haz_base  = (const float*)d_in[7];
    const float* pop_age   = (const float*)d_in[8];
    const float* population= (const float*)d_in[9];
    const float* aging     = (const float*)d_in[10];
    const float* asfr      = (const float*)d_in[11];
    const float* distance  = (const float*)d_in[12];
    const float* cw        = (const float*)d_in[13];
    const float* pw        = (const float*)d_in[14];
    const float* cbase     = (const float*)d_in[15];
    const float* lbase     = (const float*)d_in[16];
    const float* greed     = (const float*)d_in[17];
    const float* eATP      = (const float*)d_in[18];
    const float* eADP      = (const float*)d_in[19];
    const float* eAMP      = (const float*)d_in[20];
    const float* patp      = (const float*)d_in[21];
    const float* padp      = (const float*)d_in[22];
    const float* pamp      = (const float*)d_in[23];
    const int*   nbr       = (const int*)d_in[24];
    const int*   reg       = (const int*)d_in[25];

    float* O = (float*)d_out;

    // -------- workspace layout (f32 units) --------
    float* W = (float*)d_ws;
    float* Wpa    = W;                       // RR*104
    float* Wdfrac = Wpa    + RR * PAD_W;
    float* Wbsurv = Wdfrac + RR;
    float* Wattr  = Wbsurv + RR;
    float* Wdsum  = Wattr  + RR;
    float* Wgdist = Wdsum  + RR;             // RR*32
    float* Wash   = Wgdist + RR * KK;        // RR*22
    float* Wmove  = Wash   + RR * 22;        // RR*32
    float* P4f    = Wmove  + RR * KK;        // RR*4
    float* P2f    = P4f    + RR * 4;         // RR*2
    float* Wadd   = P2f    + RR * 2;         // RR*24
    float* Smig   = Wadd   + RR * 24;        // NCHUNK*22*RR
    unsigned long long* S = (unsigned long long*)(Smig + (size_t)NCHUNK * 22 * RR); // NB*RR u64

    k_region1<<<RR / 4, 256, 0, stream>>>(
        aec, gdp_pc, gdp_ema, gdp_base, dev_in, sink_use, sink_cap, haz_base,
        pop_age, population, aging, asfr, distance, nbr,
        Wpa, Wdfrac, Wbsurv, Wattr, Wgdist, Wdsum, O);

    k_migrate_a<<<RR / 4, 256, 0, stream>>>(nbr, Wattr, Wgdist, Wdsum, Wpa, Wash, Wmove);

    k_migbhist<<<NMIG + NB, 512, 0, stream>>>(
        nbr, Wash, Wmove, Smig, reg, greed, eATP, eADP, eAMP, S);

    k_reduce<<<(22 * RR) / 256, 256, 0, stream>>>(Smig, Wadd);

    k_fin<<<1024 + RR / 256, 256, 0, stream>>>(
        Wpa, Wadd, cw, pw, cbase, lbase, S, Wdfrac, Wbsurv,
        patp, padp, pamp, (float4*)P4f, (float2*)P2f, O);

    k_apply<<<(NAG / 4 + 255) / 256, 256, 0, stream>>>(
        reg, greed, eATP, eADP, eAMP, (const float4*)P4f, (const float2*)P2f, O);
}

// Round 11
// 97.118 us; speedup vs baseline: 1.4033x; 1.4033x over previous
//
#include <hip/hip_runtime.h>

#define RR 4096
#define AA 101
#define PAD_W 104
#define KK 32
#define NAG 4000000

#define NCHUNK 32
#define DR 512
#define NRANGE 8
#define EPB (RR * KK / NCHUNK)   // 4096 edges per chunk
#define NB 512                   // hist blocks
#define NMIG (NRANGE * NCHUNK)   // 256 migrate blocks
#define CH 16                    // S-reduce chunks

static constexpr float EPS  = 1e-9f;
static constexpr float DT   = 1.0f / 365.0f;
static constexpr float FRAC_MOVE = 0.02f / 365.0f;

static constexpr float SC2   = 4.0f;             // wallet quantum 0.25
static constexpr float INV2  = 0.25f;
static constexpr float SC9   = 512.0f;           // greed quantum 2^-9
static constexpr float INV9  = 1.0f / 512.0f;
static constexpr float SC18  = 262144.0f;        // 2^18 (migrate)
static constexpr float INV18 = 1.0f / 262144.0f;

// ---------------- d_out offsets (f32 elements, return order) ----------------
#define OUT_POP   0
#define OUT_POPN  413696
#define OUT_GDP   417792
#define OUT_DEV   421888
#define OUT_H     425984
#define OUT_CONS  430080
#define OUT_LAB   434176
#define OUT_PSR   438272
#define OUT_DEP   442368
#define OUT_ATP   446464
#define OUT_ADP   4446464
#define OUT_AMP   8446464
#define OUT_PATP  12446464
#define OUT_PADP  12450560
#define OUT_PAMP  12454656

static __device__ __forceinline__ float clampf(float x, float lo, float hi) {
    return fminf(fmaxf(x, lo), hi);
}
static __device__ __forceinline__ float wred(float x) {
#pragma unroll
    for (int m = 32; m; m >>= 1) x += __shfl_xor(x, m);
    return x;
}

// ---------------- kernel 1: per-region stage 1, wave-per-region ----------------
__global__ __launch_bounds__(256) void k_region1(
    const float* __restrict__ aec, const float* __restrict__ gdp_pc,
    const float* __restrict__ gdp_ema_in, const float* __restrict__ gdp_base,
    const float* __restrict__ dev_in, const float* __restrict__ sink_use,
    const float* __restrict__ sink_cap, const float* __restrict__ haz_base,
    const float* __restrict__ pop_age, const float* __restrict__ population,
    const float* __restrict__ aging, const float* __restrict__ asfr,
    const float* __restrict__ distance, const int* __restrict__ nbr,
    float* __restrict__ Wpa, float* __restrict__ Wdfrac, float* __restrict__ Wbsurv,
    float* __restrict__ Wattr, float* __restrict__ Wgdist, float* __restrict__ Wdsum,
    float* __restrict__ O)
{
    int wid = threadIdx.x >> 6, lane = threadIdx.x & 63;
    int r = blockIdx.x * 4 + wid;

    float aec_norm = clampf(aec[r], 0.0f, 1.0f);
    float gprev = gdp_ema_in[r];
    float gema  = gprev * 0.9f + 0.1f * gdp_pc[r];
    float base  = gdp_base[r];
    float g_ratio = logf(fmaxf(gema / (base + EPS), 1e-6f));
    float g_term  = clampf(0.5f + 0.5f * tanhf(0.5f * g_ratio), 0.0f, 1.0f);
    float util = clampf(sink_use[r] / (sink_cap[r] + EPS), 0.0f, 1.0f);
    float H = clampf(0.5f * aec_norm + 0.4f * g_term + 0.1f * (1.0f - util), 0.0f, 1.0f);
    float dev_proxy = clampf(0.5f + 0.5f * tanhf(0.3f * g_ratio), 0.0f, 1.0f);
    float dev = dev_in[r] * 0.99f + 0.01f * dev_proxy;

    float m_neon  = expf(-2.0f * H);
    float m_child = expf(-1.5f * H);
    float m_adult = expf(-1.0f * H);
    float hazmul = 1.0f + 0.5f * util;

    int a0 = lane * 2, a1 = a0 + 1;
    bool v0 = (a0 < AA), v1 = (a1 < AA);

    float p0 = 0.f, p1 = 0.f, hz0 = 0.f, hz1 = 0.f;
    if (v0) {
        p0 = pop_age[r * AA + a0];
        float mult = (a0 == 0) ? m_neon : ((a0 < 15) ? m_child : m_adult);
        hz0 = clampf(haz_base[a0] * mult * hazmul, 0.0f, 5.0f);
    }
    if (v1) {
        p1 = pop_age[r * AA + a1];
        float mult = (a1 < 15) ? m_child : m_adult;
        hz1 = clampf(haz_base[a1] * mult * hazmul, 0.0f, 5.0f);
    }
    float s0 = v0 ? p0 * expf(-hz0 * DT) : 0.f;
    float s1 = v1 ? p1 * expf(-hz1 * DT) : 0.f;
    float sp = __shfl_up(s1, 1);   // s[a0-1]

    float Md0 = 0.f, Md1 = 0.f, Ms0 = 0.f, Ms1 = 0.f;
    if (v0) { Md0 = aging[a0 * AA + a0]; if (a0 > 0) Ms0 = aging[(a0 - 1) * AA + a0]; }
    if (v1) { Md1 = aging[a1 * AA + a1]; Ms1 = aging[(a1 - 1) * AA + a1]; }

    float pa0 = v0 ? ((a0 == 0) ? s0 * Md0 : s0 * Md0 + sp * Ms0) : 0.f;
    float pa1 = v1 ? (s1 * Md1 + s0 * Ms1) : 0.f;

    if (v0 && a0 > 0) Wpa[r * PAD_W + a0] = pa0;
    if (v1)           Wpa[r * PAD_W + a1] = pa1;

    float pop_sum  = wred(p0 + p1);
    float surv_sum = wred(s0 + s1);
    float haz05 = wred(((v0 && a0 < 5) ? hz0 : 0.f) + ((v1 && a1 < 5) ? hz1 : 0.f));
    float bs0 = (a0 >= 15 && a0 < 50) ? 0.5f * pa0 * asfr[a0 - 15] : 0.f;
    float bs1 = (a1 >= 15 && a1 < 50) ? 0.5f * pa1 * asfr[a1 - 15] : 0.f;
    float b_sum = wred(bs0 + bs1);

    float dc = 0.f;
    if (lane < KK) {
        int idx = nbr[r * KK + lane];
        float d = distance[(size_t)r * RR + idx];
        Wgdist[r * KK + lane] = d;
        dc = d;
    }
    float dsum = wred(dc);

    if (lane == 0) {
        O[OUT_GDP + r] = gema;
        O[OUT_DEV + r] = dev;
        O[OUT_H + r]   = H;

        float deaths = fmaxf(pop_sum - surv_sum, 0.0f);
        Wdfrac[r] = clampf(deaths / (population[r] + EPS), 0.0f, 0.99f);

        float surv_u5 = expf(-haz05);
        float F_dev = clampf(expf(-dev), 0.5f, 1.5f);
        float F_rep = clampf(0.995f / fmaxf(surv_u5, 0.001f), 0.5f, 1.8f);
        float g_growth = logf(fmaxf(gema + EPS, 1e-6f)) - logf(fmaxf(gprev + EPS, 1e-6f));
        float F_cyc = clampf(expf(-5.0f * fmaxf(-g_growth, 0.0f)), 0.6f, 1.2f);
        float F_total = clampf(F_dev * F_rep * F_cyc, 0.4f, 1.8f);
        float births = fmaxf(b_sum * F_total * DT, 0.0f);
        float bsurv = births * expf(-hz0 * DT);       // hz0 on lane0 = haz[0]
        Wbsurv[r] = bsurv;
        Wpa[r * PAD_W + 0] = pa0 + bsurv;             // lane0 pa0 = pa(age 0)

        Wattr[r] = 0.6f * (gdp_pc[r] / (base + EPS)) + 0.4f * (0.5f + 0.5f * aec_norm);
        Wdsum[r] = dsum;
    }
}

// ---------------- kernel 2a: migration weights + outflow (means inlined) ----------------
__global__ __launch_bounds__(256) void k_migrate_a(
    const int* __restrict__ nbr, const float* __restrict__ Wattr,
    const float* __restrict__ Wgdist, const float* __restrict__ Wdsum,
    float* __restrict__ Wpa, float* __restrict__ Wash, float* __restrict__ Wmove)
{
    __shared__ float sred[8];
    int t = threadIdx.x;
    {
        float a = 0.f, d = 0.f;
        for (int i = t; i < RR; i += 256) { a += Wattr[i]; d += Wdsum[i]; }
        a = wred(a); d = wred(d);
        int w0 = t >> 6;
        if ((t & 63) == 0) { sred[w0] = a; sred[4 + w0] = d; }
    }
    __syncthreads();
    float asum = sred[0] + sred[1] + sred[2] + sred[3];
    float dall = sred[4] + sred[5] + sred[6] + sred[7];
    float inv_am = 1.0f / (asum / (float)RR + EPS);
    float inv_dm = 1.0f / (dall / (float)(RR * KK) + EPS);

    int wid = t >> 6, lane = t & 63;
    int r = blockIdx.x * 4 + wid;

    float mob = 0.f;
    if (lane < 22) mob = Wpa[r * PAD_W + 18 + lane];
    float msum = wred(lane < 22 ? mob : 0.f);

    float w = 0.f;
    if (lane < KK) {
        int idx = nbr[r * KK + lane];
        float an = Wattr[idx] * inv_am;
        float cost = 1.0f + Wgdist[r * KK + lane] * inv_dm;
        w = fmaxf(an / cost, 0.0f);
    }
    float wsum = wred(lane < KK ? w : 0.f);

    float out_R = msum * FRAC_MOVE;
    float invw = 1.0f / (wsum + EPS);
    float move_sum = out_R * wsum * invw;
    float inv_ms = 1.0f / (msum + EPS);

    if (lane < 22) {
        float ash = mob * inv_ms;
        Wash[r * 22 + lane] = ash;
        Wpa[r * PAD_W + 18 + lane] = mob - ash * move_sum;
    }
    if (lane < KK) Wmove[r * KK + lane] = out_R * w * invw;
}

// ---------------- kernel 3: FUSED inflow scatter + agent segment sums ----------------
__global__ __launch_bounds__(512) void k_migbhist(
    const int* __restrict__ nbr, const float* __restrict__ Wash,
    const float* __restrict__ Wmove, float* __restrict__ Smig,
    const int* __restrict__ reg, const float* __restrict__ greed,
    const float* __restrict__ atp, const float* __restrict__ adp,
    const float* __restrict__ amp, unsigned long long* __restrict__ S)
{
    __shared__ unsigned long long h[11 * DR];   // 45056 B (hist uses first RR=4096)
    int bid = blockIdx.x;

    if (bid < NMIG) {
        int range = bid & (NRANGE - 1);
        int chunk = bid >> 3;
        int d0 = range * DR;

        for (int i = threadIdx.x; i < 11 * DR; i += 512) h[i] = 0ull;
        __syncthreads();

        int tend = (chunk + 1) * EPB;
        for (int t = chunk * EPB + threadIdx.x; t < tend; t += 512) {
            int idx = nbr[t];
            if (idx >= d0 && idx < d0 + DR) {
                int rsrc = t >> 5;
                float mv = Wmove[t];
                const float* ash = &Wash[rsrc * 22];
                int dl = idx - d0;
#pragma unroll
                for (int f = 0; f < 11; f++) {
                    unsigned long long lo = __float2uint_rn(ash[2 * f] * mv * SC18);
                    unsigned long long hi = __float2uint_rn(ash[2 * f + 1] * mv * SC18);
                    atomicAdd(&h[f * DR + dl], lo | (hi << 32));
                }
            }
        }
        __syncthreads();

        for (int i = threadIdx.x; i < 11 * DR; i += 512) {
            int f = i / DR, d = i - f * DR;
            unsigned long long v = h[i];
            Smig[(chunk * 22 + 2 * f) * RR + d0 + d]     = (float)(unsigned int)v * INV18;
            Smig[(chunk * 22 + 2 * f + 1) * RR + d0 + d] = (float)(v >> 32) * INV18;
        }
    } else {
        int b = bid - NMIG;
        for (int i = threadIdx.x; i < RR; i += 512) h[i] = 0ull;
        __syncthreads();

        const int4*   reg4 = (const int4*)reg;
        const float4* g4 = (const float4*)greed;
        const float4* a4 = (const float4*)atp;
        const float4* d4 = (const float4*)adp;
        const float4* m4 = (const float4*)amp;
        const int NQ = NAG / 4;
        const int STRIDE = NB * 512;

        for (int q = b * 512 + threadIdx.x; q < NQ; q += STRIDE) {
            int4 rr = reg4[q];
            float4 gv = g4[q], av = a4[q], dv = d4[q], mv = m4[q];
#define DO1(RX, GX, AX, DX, MX) { \
            unsigned long long ai = __float2uint_rn((AX) * SC2); \
            unsigned long long di = __float2uint_rn((DX) * SC2); \
            unsigned long long mi = __float2uint_rn((MX) * SC2); \
            unsigned long long gi = __float2uint_rn(((GX) + 1e-9f) * SC9); \
            atomicAdd(&h[RX], ai | (di << 14) | (mi << 28) | (gi << 42) | (1ull << 56)); }
            DO1(rr.x, gv.x, av.x, dv.x, mv.x)
            DO1(rr.y, gv.y, av.y, dv.y, mv.y)
            DO1(rr.z, gv.z, av.z, dv.z, mv.z)
            DO1(rr.w, gv.w, av.w, dv.w, mv.w)
#undef DO1
        }
        __syncthreads();

        for (int i = threadIdx.x; i < RR; i += 512)
            S[(size_t)b * RR + i] = h[i];
    }
}

// ---------------- kernel 4: S->T decode-reduce (256 blks) + Smig->Wadd fold (352 blks) ----------------
__global__ __launch_bounds__(256) void k_reduce(
    const unsigned long long* __restrict__ S, const float* __restrict__ Smig,
    float* __restrict__ T, float* __restrict__ Wadd)
{
    int blk = blockIdx.x;
    if (blk < 256) {
        int tid = blk * 256 + threadIdx.x;      // < 16*4096
        int r = tid & (RR - 1);
        int c = tid >> 12;                      // chunk in [0,16)
        const int bpc = NB / CH;                // 32
        float sa = 0.f, sd = 0.f, sm = 0.f, sg = 0.f, sc = 0.f;
        for (int b = c * bpc; b < (c + 1) * bpc; b++) {
            unsigned long long p = S[(size_t)b * RR + r];
            sa += (float)(unsigned int)(p & 0x3FFFull);
            sd += (float)(unsigned int)((p >> 14) & 0x3FFFull);
            sm += (float)(unsigned int)((p >> 28) & 0x3FFFull);
            sg += (float)(unsigned int)((p >> 42) & 0x3FFFull);
            sc += (float)(unsigned int)(p >> 56);
        }
        T[(0 * CH + c) * RR + r] = sa * INV2;
        T[(1 * CH + c) * RR + r] = sd * INV2;
        T[(2 * CH + c) * RR + r] = sm * INV2;
        T[(3 * CH + c) * RR + r] = sg * INV9;
        T[(4 * CH + c) * RR + r] = sc;
    } else {
        int t2 = (blk - 256) * 256 + threadIdx.x;   // < 22*4096
        int f = t2 >> 12, rr = t2 & (RR - 1);
        float acc = 0.f;
#pragma unroll
        for (int c = 0; c < NCHUNK; c++)
            acc += Smig[(c * 22 + f) * RR + rr];
        Wadd[rr * 24 + f] = acc;
    }
}

// ---------------- kernel 5: finalize population (wave/region) + region2-from-T ----------------
__global__ __launch_bounds__(256) void k_fin(
    const float* __restrict__ Wpa, const float* __restrict__ Wadd,
    const float* __restrict__ cw, const float* __restrict__ pw,
    const float* __restrict__ cbase, const float* __restrict__ lbase,
    const float* __restrict__ T,
    const float* __restrict__ Wdfrac, const float* __restrict__ Wbsurv,
    const float* __restrict__ patp, const float* __restrict__ padp,
    const float* __restrict__ pamp,
    float4* __restrict__ P4, float2* __restrict__ P2,
    float* __restrict__ O)
{
    int blk = blockIdx.x;
    if (blk < 1024) {
        int wid = threadIdx.x >> 6, lane = threadIdx.x & 63;
        int r = blk * 4 + wid;
        int a0 = lane * 2, a1 = a0 + 1;
        bool v0 = (a0 < AA), v1 = (a1 < AA);

        float va = 0.f, vb = 0.f;
        if (lane < 51) {
            float2 pp = *(const float2*)&Wpa[r * PAD_W + a0];
            va = pp.x; vb = pp.y;
        }
        if (a0 >= 18 && a0 < 40) {
            float2 ad = *(const float2*)&Wadd[r * 24 + (a0 - 18)];
            va += ad.x; vb += ad.y;
        }
        va = v0 ? fmaxf(va, 0.0f) : 0.f;
        vb = v1 ? fmaxf(vb, 0.0f) : 0.f;
        if (v0) O[OUT_POP + r * AA + a0] = va;
        if (v1) O[OUT_POP + r * AA + a1] = vb;

        float cw0 = v0 ? cw[a0] : 0.f, cw1 = v1 ? cw[a1] : 0.f;
        float pw0 = v0 ? pw[a0] : 0.f, pw1 = v1 ? pw[a1] : 0.f;

        float psum  = wred(va + vb);
        float cdot  = wred(va * cw0 + vb * cw1);
        float ldot  = wred(va * pw0 + vb * pw1);
        float young = wred(((a0 < 15) ? va : 0.f) + ((a1 < 15) ? vb : 0.f));
        float work  = wred(((a0 >= 15 && a0 < 65) ? va : 0.f) + ((a1 >= 15 && a1 < 65) ? vb : 0.f));
        float old   = wred(((a0 >= 65) ? va : 0.f) + ((a1 >= 65) ? vb : 0.f));

        if (lane == 0) {
            O[OUT_POPN + r] = fmaxf(psum, 0.0f);
            O[OUT_CONS + r] = clampf(cdot / (cbase[r] + EPS), 0.25f, 4.0f);
            O[OUT_LAB + r]  = clampf(ldot / (lbase[r] + EPS), 0.2f, 1.2f);
            O[OUT_PSR + r]  = work / (old + EPS);
            O[OUT_DEP + r]  = (young + old) / (work + EPS);
        }
    } else {
        int r = (blk - 1024) * 256 + threadIdx.x;
        if (r >= RR) return;
        float sums[5];
#pragma unroll
        for (int s = 0; s < 5; s++) {
            float acc = 0.f;
#pragma unroll
            for (int c = 0; c < CH; c++)
                acc += T[(s * CH + c) * RR + r];
            sums[s] = acc;
        }
        float dfi = Wdfrac[r];
        float ra = sums[0] * dfi;
        float rd = sums[1] * dfi;
        float rm = sums[2] * dfi;
        O[OUT_PATP + r] = patp[r] - ra * 0.2f;
        O[OUT_PADP + r] = padp[r] - rd * 0.2f;
        O[OUT_PAMP + r] = pamp[r] - rm * 0.2f;
        P4[r] = make_float4(1.0f - dfi, 1.0f / (sums[3] + EPS), ra * 0.8f, rd * 0.8f);
        P2[r] = make_float2(rm * 0.8f, Wbsurv[r] / fmaxf(sums[4], 1.0f));
    }
}

// ---------------- kernel 6: agent apply, float4 ----------------
__global__ __launch_bounds__(256) void k_apply(
    const int* __restrict__ reg, const float* __restrict__ greed,
    const float* __restrict__ atp, const float* __restrict__ adp,
    const float* __restrict__ amp,
    const float4* __restrict__ P4, const float2* __restrict__ P2,
    float* __restrict__ O)
{
    int q = blockIdx.x * 256 + threadIdx.x;
    if (q >= NAG / 4) return;
    int4 rr = ((const int4*)reg)[q];
    float4 g = ((const float4*)greed)[q];
    float4 a = ((const float4*)atp)[q];
    float4 d = ((const float4*)adp)[q];
    float4 m = ((const float4*)amp)[q];
    float4 oa, od, om;
#define ONE(c) { float4 t4 = P4[rr.c]; float2 t2 = P2[rr.c]; \
    float wn = (g.c + 1e-9f) * t4.y; \
    oa.c = a.c * t4.x + wn * t4.z + t2.y; \
    od.c = d.c * t4.x + wn * t4.w; \
    om.c = m.c * t4.x + wn * t2.x; }
    ONE(x) ONE(y) ONE(z) ONE(w)
#undef ONE
    ((float4*)(O + OUT_ATP))[q] = oa;
    ((float4*)(O + OUT_ADP))[q] = od;
    ((float4*)(O + OUT_AMP))[q] = om;
}

extern "C" void kernel_launch(void* const* d_in, const int* in_sizes, int n_in,
                              void* d_out, int out_size, void* d_ws, size_t ws_size,
                              hipStream_t stream) {
    const float* aec       = (const float*)d_in[0];
    const float* gdp_pc    = (const float*)d_in[1];
    const float* gdp_ema   = (const float*)d_in[2];
    const float* gdp_base  = (const float*)d_in[3];
    const float* dev_in    = (const float*)d_in[4];
    const float* sink_use  = (const float*)d_in[5];
    const float* sink_cap  = (const float*)d_in[6];
    const float* haz_base  = (const float*)d_in[7];
    const float* pop_age   = (const float*)d_in[8];
    const float* population= (const float*)d_in[9];
    const float* aging     = (const float*)d_in[10];
    const float* asfr      = (const float*)d_in[11];
    const float* distance  = (const float*)d_in[12];
    const float* cw        = (const float*)d_in[13];
    const float* pw        = (const float*)d_in[14];
    const float* cbase     = (const float*)d_in[15];
    const float* lbase     = (const float*)d_in[16];
    const float* greed     = (const float*)d_in[17];
    const float* eATP      = (const float*)d_in[18];
    const float* eADP      = (const float*)d_in[19];
    const float* eAMP      = (const float*)d_in[20];
    const float* patp      = (const float*)d_in[21];
    const float* padp      = (const float*)d_in[22];
    const float* pamp      = (const float*)d_in[23];
    const int*   nbr       = (const int*)d_in[24];
    const int*   reg       = (const int*)d_in[25];

    float* O = (float*)d_out;

    // -------- workspace layout (f32 units) --------
    float* W = (float*)d_ws;
    float* Wpa    = W;                       // RR*104
    float* Wdfrac = Wpa    + RR * PAD_W;
    float* Wbsurv = Wdfrac + RR;
    float* Wattr  = Wbsurv + RR;
    float* Wdsum  = Wattr  + RR;
    float* Wgdist = Wdsum  + RR;             // RR*32
    float* Wash   = Wgdist + RR * KK;        // RR*22
    float* Wmove  = Wash   + RR * 22;        // RR*32
    float* P4f    = Wmove  + RR * KK;        // RR*4
    float* P2f    = P4f    + RR * 4;         // RR*2
    float* Wadd   = P2f    + RR * 2;         // RR*24
    float* T      = Wadd   + RR * 24;        // 5*CH*RR
    float* Smig   = T      + 5 * CH * RR;    // NCHUNK*22*RR
    unsigned long long* S = (unsigned long long*)(Smig + (size_t)NCHUNK * 22 * RR); // NB*RR u64

    k_region1<<<RR / 4, 256, 0, stream>>>(
        aec, gdp_pc, gdp_ema, gdp_base, dev_in, sink_use, sink_cap, haz_base,
        pop_age, population, aging, asfr, distance, nbr,
        Wpa, Wdfrac, Wbsurv, Wattr, Wgdist, Wdsum, O);

    k_migrate_a<<<RR / 4, 256, 0, stream>>>(nbr, Wattr, Wgdist, Wdsum, Wpa, Wash, Wmove);

    k_migbhist<<<NMIG + NB, 512, 0, stream>>>(
        nbr, Wash, Wmove, Smig, reg, greed, eATP, eADP, eAMP, S);

    k_reduce<<<256 + (22 * RR) / 256, 256, 0, stream>>>(S, Smig, T, Wadd);

    k_fin<<<1024 + RR / 256, 256, 0, stream>>>(
        Wpa, Wadd, cw, pw, cbase, lbase, T, Wdfrac, Wbsurv,
        patp, padp, pamp, (float4*)P4f, (float2*)P2f, O);

    k_apply<<<(NAG / 4 + 255) / 256, 256, 0, stream>>>(
        reg, greed, eATP, eADP, eAMP, (const float4*)P4f, (const float2*)P2f, O);
}

// Round 12
// 92.807 us; speedup vs baseline: 1.4685x; 1.0464x over previous
//
#include <hip/hip_runtime.h>

#define RR 4096
#define AA 101
#define PAD_W 104
#define KK 32
#define NAG 4000000

#define NCHUNK 32
#define DR 512
#define NRANGE 8
#define EPB (RR * KK / NCHUNK)   // 4096 edges per chunk
#define NB 512                   // hist blocks
#define NMIG (NRANGE * NCHUNK)   // 256 migrate blocks
#define CH 16                    // S-reduce chunks

static constexpr float EPS  = 1e-9f;
static constexpr float DT   = 1.0f / 365.0f;
static constexpr float FRAC_MOVE = 0.02f / 365.0f;

static constexpr float SC2   = 4.0f;             // wallet quantum 0.25
static constexpr float INV2  = 0.25f;
static constexpr float SC9   = 512.0f;           // greed quantum 2^-9
static constexpr float INV9  = 1.0f / 512.0f;
static constexpr float SC18  = 262144.0f;        // 2^18 (migrate)
static constexpr float INV18 = 1.0f / 262144.0f;

// ---------------- d_out offsets (f32 elements, return order) ----------------
#define OUT_POP   0
#define OUT_POPN  413696
#define OUT_GDP   417792
#define OUT_DEV   421888
#define OUT_H     425984
#define OUT_CONS  430080
#define OUT_LAB   434176
#define OUT_PSR   438272
#define OUT_DEP   442368
#define OUT_ATP   446464
#define OUT_ADP   4446464
#define OUT_AMP   8446464
#define OUT_PATP  12446464
#define OUT_PADP  12450560
#define OUT_PAMP  12454656

static __device__ __forceinline__ float clampf(float x, float lo, float hi) {
    return fminf(fmaxf(x, lo), hi);
}
static __device__ __forceinline__ float wred(float x) {
#pragma unroll
    for (int m = 32; m; m >>= 1) x += __shfl_xor(x, m);
    return x;
}

// ---------------- kernel 1: FUSED region1 (blocks [0,1024)) + agent hist (blocks [1024,1024+NB)) ----------------
__global__ __launch_bounds__(256) void k_r1hist(
    const float* __restrict__ aec, const float* __restrict__ gdp_pc,
    const float* __restrict__ gdp_ema_in, const float* __restrict__ gdp_base,
    const float* __restrict__ dev_in, const float* __restrict__ sink_use,
    const float* __restrict__ sink_cap, const float* __restrict__ haz_base,
    const float* __restrict__ pop_age, const float* __restrict__ population,
    const float* __restrict__ aging, const float* __restrict__ asfr,
    const float* __restrict__ distance, const int* __restrict__ nbr,
    float* __restrict__ Wpa, float* __restrict__ Wdfrac, float* __restrict__ Wbsurv,
    float* __restrict__ Wattr, float* __restrict__ Wgdist, float* __restrict__ Wdsum,
    const int* __restrict__ reg, const float* __restrict__ greed,
    const float* __restrict__ atp, const float* __restrict__ adp,
    const float* __restrict__ amp, unsigned long long* __restrict__ S,
    float* __restrict__ O)
{
    __shared__ unsigned long long h[RR];      // 32 KiB (hist role only)
    int blk = blockIdx.x;

    if (blk < 1024) {
        // ---- region1 role: 4 regions per block, wave per region ----
        int wid = threadIdx.x >> 6, lane = threadIdx.x & 63;
        int r = blk * 4 + wid;

        float aec_norm = clampf(aec[r], 0.0f, 1.0f);
        float gprev = gdp_ema_in[r];
        float gema  = gprev * 0.9f + 0.1f * gdp_pc[r];
        float base  = gdp_base[r];
        float g_ratio = logf(fmaxf(gema / (base + EPS), 1e-6f));
        float g_term  = clampf(0.5f + 0.5f * tanhf(0.5f * g_ratio), 0.0f, 1.0f);
        float util = clampf(sink_use[r] / (sink_cap[r] + EPS), 0.0f, 1.0f);
        float H = clampf(0.5f * aec_norm + 0.4f * g_term + 0.1f * (1.0f - util), 0.0f, 1.0f);
        float dev_proxy = clampf(0.5f + 0.5f * tanhf(0.3f * g_ratio), 0.0f, 1.0f);
        float dev = dev_in[r] * 0.99f + 0.01f * dev_proxy;

        float m_neon  = expf(-2.0f * H);
        float m_child = expf(-1.5f * H);
        float m_adult = expf(-1.0f * H);
        float hazmul = 1.0f + 0.5f * util;

        int a0 = lane * 2, a1 = a0 + 1;
        bool v0 = (a0 < AA), v1 = (a1 < AA);

        float p0 = 0.f, p1 = 0.f, hz0 = 0.f, hz1 = 0.f;
        if (v0) {
            p0 = pop_age[r * AA + a0];
            float mult = (a0 == 0) ? m_neon : ((a0 < 15) ? m_child : m_adult);
            hz0 = clampf(haz_base[a0] * mult * hazmul, 0.0f, 5.0f);
        }
        if (v1) {
            p1 = pop_age[r * AA + a1];
            float mult = (a1 < 15) ? m_child : m_adult;
            hz1 = clampf(haz_base[a1] * mult * hazmul, 0.0f, 5.0f);
        }
        float s0 = v0 ? p0 * expf(-hz0 * DT) : 0.f;
        float s1 = v1 ? p1 * expf(-hz1 * DT) : 0.f;
        float sp = __shfl_up(s1, 1);   // s[a0-1]

        float Md0 = 0.f, Md1 = 0.f, Ms0 = 0.f, Ms1 = 0.f;
        if (v0) { Md0 = aging[a0 * AA + a0]; if (a0 > 0) Ms0 = aging[(a0 - 1) * AA + a0]; }
        if (v1) { Md1 = aging[a1 * AA + a1]; Ms1 = aging[(a1 - 1) * AA + a1]; }

        float pa0 = v0 ? ((a0 == 0) ? s0 * Md0 : s0 * Md0 + sp * Ms0) : 0.f;
        float pa1 = v1 ? (s1 * Md1 + s0 * Ms1) : 0.f;

        if (v0 && a0 > 0) Wpa[r * PAD_W + a0] = pa0;
        if (v1)           Wpa[r * PAD_W + a1] = pa1;

        float pop_sum  = wred(p0 + p1);
        float surv_sum = wred(s0 + s1);
        float haz05 = wred(((v0 && a0 < 5) ? hz0 : 0.f) + ((v1 && a1 < 5) ? hz1 : 0.f));
        float bs0 = (a0 >= 15 && a0 < 50) ? 0.5f * pa0 * asfr[a0 - 15] : 0.f;
        float bs1 = (a1 >= 15 && a1 < 50) ? 0.5f * pa1 * asfr[a1 - 15] : 0.f;
        float b_sum = wred(bs0 + bs1);

        float dc = 0.f;
        if (lane < KK) {
            int idx = nbr[r * KK + lane];
            float d = distance[(size_t)r * RR + idx];
            Wgdist[r * KK + lane] = d;
            dc = d;
        }
        float dsum = wred(dc);

        if (lane == 0) {
            O[OUT_GDP + r] = gema;
            O[OUT_DEV + r] = dev;
            O[OUT_H + r]   = H;

            float deaths = fmaxf(pop_sum - surv_sum, 0.0f);
            Wdfrac[r] = clampf(deaths / (population[r] + EPS), 0.0f, 0.99f);

            float surv_u5 = expf(-haz05);
            float F_dev = clampf(expf(-dev), 0.5f, 1.5f);
            float F_rep = clampf(0.995f / fmaxf(surv_u5, 0.001f), 0.5f, 1.8f);
            float g_growth = logf(fmaxf(gema + EPS, 1e-6f)) - logf(fmaxf(gprev + EPS, 1e-6f));
            float F_cyc = clampf(expf(-5.0f * fmaxf(-g_growth, 0.0f)), 0.6f, 1.2f);
            float F_total = clampf(F_dev * F_rep * F_cyc, 0.4f, 1.8f);
            float births = fmaxf(b_sum * F_total * DT, 0.0f);
            float bsurv = births * expf(-hz0 * DT);       // hz0 on lane0 = haz[0]
            Wbsurv[r] = bsurv;
            Wpa[r * PAD_W + 0] = pa0 + bsurv;             // lane0 pa0 = pa(age 0)

            Wattr[r] = 0.6f * (gdp_pc[r] / (base + EPS)) + 0.4f * (0.5f + 0.5f * aec_norm);
            Wdsum[r] = dsum;
        }
    } else {
        // ---- hist role: ONE u64 atomic per agent, 2-deep software pipeline ----
        int b = blk - 1024;
        for (int i = threadIdx.x; i < RR; i += 256) h[i] = 0ull;
        __syncthreads();

        const int4*   reg4 = (const int4*)reg;
        const float4* g4 = (const float4*)greed;
        const float4* a4 = (const float4*)atp;
        const float4* d4 = (const float4*)adp;
        const float4* m4 = (const float4*)amp;
        const int NQ = NAG / 4;
        const int STRIDE = NB * 256;

        int q = b * 256 + threadIdx.x;
        if (q < NQ) {
            int4 rA = reg4[q];
            float4 gA = g4[q], aA = a4[q], dA = d4[q], mA = m4[q];
            while (true) {
                int qn = q + STRIDE;
                bool more = (qn < NQ);
                int qs = more ? qn : q;
                // issue next-iteration loads BEFORE consuming current
                int4 rB = reg4[qs];
                float4 gB = g4[qs], aB = a4[qs], dB = d4[qs], mB = m4[qs];
#define DO1(RX, GX, AX, DX, MX) { \
                unsigned long long ai = __float2uint_rn((AX) * SC2); \
                unsigned long long di = __float2uint_rn((DX) * SC2); \
                unsigned long long mi = __float2uint_rn((MX) * SC2); \
                unsigned long long gi = __float2uint_rn(((GX) + 1e-9f) * SC9); \
                atomicAdd(&h[RX], ai | (di << 14) | (mi << 28) | (gi << 42) | (1ull << 56)); }
                DO1(rA.x, gA.x, aA.x, dA.x, mA.x)
                DO1(rA.y, gA.y, aA.y, dA.y, mA.y)
                DO1(rA.z, gA.z, aA.z, dA.z, mA.z)
                DO1(rA.w, gA.w, aA.w, dA.w, mA.w)
#undef DO1
                if (!more) break;
                rA = rB; gA = gB; aA = aB; dA = dB; mA = mB;
                q = qn;
            }
        }
        __syncthreads();

        for (int i = threadIdx.x; i < RR; i += 256)
            S[(size_t)b * RR + i] = h[i];
    }
}

// ---------------- kernel 2: migration weights + outflow (means inlined) ----------------
__global__ __launch_bounds__(256) void k_migrate_a(
    const int* __restrict__ nbr, const float* __restrict__ Wattr,
    const float* __restrict__ Wgdist, const float* __restrict__ Wdsum,
    float* __restrict__ Wpa, float* __restrict__ Wash, float* __restrict__ Wmove)
{
    __shared__ float sred[8];
    int t = threadIdx.x;
    {
        float a = 0.f, d = 0.f;
        for (int i = t; i < RR; i += 256) { a += Wattr[i]; d += Wdsum[i]; }
        a = wred(a); d = wred(d);
        int w0 = t >> 6;
        if ((t & 63) == 0) { sred[w0] = a; sred[4 + w0] = d; }
    }
    __syncthreads();
    float asum = sred[0] + sred[1] + sred[2] + sred[3];
    float dall = sred[4] + sred[5] + sred[6] + sred[7];
    float inv_am = 1.0f / (asum / (float)RR + EPS);
    float inv_dm = 1.0f / (dall / (float)(RR * KK) + EPS);

    int wid = t >> 6, lane = t & 63;
    int r = blockIdx.x * 4 + wid;

    float mob = 0.f;
    if (lane < 22) mob = Wpa[r * PAD_W + 18 + lane];
    float msum = wred(lane < 22 ? mob : 0.f);

    float w = 0.f;
    if (lane < KK) {
        int idx = nbr[r * KK + lane];
        float an = Wattr[idx] * inv_am;
        float cost = 1.0f + Wgdist[r * KK + lane] * inv_dm;
        w = fmaxf(an / cost, 0.0f);
    }
    float wsum = wred(lane < KK ? w : 0.f);

    float out_R = msum * FRAC_MOVE;
    float invw = 1.0f / (wsum + EPS);
    float move_sum = out_R * wsum * invw;
    float inv_ms = 1.0f / (msum + EPS);

    if (lane < 22) {
        float ash = mob * inv_ms;
        Wash[r * 22 + lane] = ash;
        Wpa[r * PAD_W + 18 + lane] = mob - ash * move_sum;
    }
    if (lane < KK) Wmove[r * KK + lane] = out_R * w * invw;
}

// ---------------- kernel 3: FUSED migrate_b (blocks [0,NMIG)) + S->T decode (blocks [NMIG,NMIG+128)) ----------------
__global__ __launch_bounds__(512) void k_mbdec(
    const int* __restrict__ nbr, const float* __restrict__ Wash,
    const float* __restrict__ Wmove, float* __restrict__ Smig,
    const unsigned long long* __restrict__ S, float* __restrict__ T)
{
    __shared__ unsigned long long h[11 * DR];   // 45056 B (migrate role only)
    int bid = blockIdx.x;

    if (bid < NMIG) {
        int range = bid & (NRANGE - 1);
        int chunk = bid >> 3;
        int d0 = range * DR;

        for (int i = threadIdx.x; i < 11 * DR; i += 512) h[i] = 0ull;
        __syncthreads();

        int tend = (chunk + 1) * EPB;
        for (int t = chunk * EPB + threadIdx.x; t < tend; t += 512) {
            int idx = nbr[t];
            if (idx >= d0 && idx < d0 + DR) {
                int rsrc = t >> 5;
                float mv = Wmove[t];
                const float* ash = &Wash[rsrc * 22];
                int dl = idx - d0;
#pragma unroll
                for (int f = 0; f < 11; f++) {
                    unsigned long long lo = __float2uint_rn(ash[2 * f] * mv * SC18);
                    unsigned long long hi = __float2uint_rn(ash[2 * f + 1] * mv * SC18);
                    atomicAdd(&h[f * DR + dl], lo | (hi << 32));
                }
            }
        }
        __syncthreads();

        for (int i = threadIdx.x; i < 11 * DR; i += 512) {
            int f = i / DR, d = i - f * DR;
            unsigned long long v = h[i];
            Smig[(chunk * 22 + 2 * f) * RR + d0 + d]     = (float)(unsigned int)v * INV18;
            Smig[(chunk * 22 + 2 * f + 1) * RR + d0 + d] = (float)(v >> 32) * INV18;
        }
    } else {
        int tid = (bid - NMIG) * 512 + threadIdx.x;   // < 16*4096
        int r = tid & (RR - 1);
        int c = tid >> 12;                            // chunk in [0,16)
        const int bpc = NB / CH;                      // 32
        float sa = 0.f, sd = 0.f, sm = 0.f, sg = 0.f, sc = 0.f;
        for (int b = c * bpc; b < (c + 1) * bpc; b++) {
            unsigned long long p = S[(size_t)b * RR + r];
            sa += (float)(unsigned int)(p & 0x3FFFull);
            sd += (float)(unsigned int)((p >> 14) & 0x3FFFull);
            sm += (float)(unsigned int)((p >> 28) & 0x3FFFull);
            sg += (float)(unsigned int)((p >> 42) & 0x3FFFull);
            sc += (float)(unsigned int)(p >> 56);
        }
        T[(0 * CH + c) * RR + r] = sa * INV2;
        T[(1 * CH + c) * RR + r] = sd * INV2;
        T[(2 * CH + c) * RR + r] = sm * INV2;
        T[(3 * CH + c) * RR + r] = sg * INV9;
        T[(4 * CH + c) * RR + r] = sc;
    }
}

// ---------------- kernel 4: fold Smig -> Wadd (coalesced) ----------------
__global__ __launch_bounds__(256) void k_fold(
    const float* __restrict__ Smig, float* __restrict__ Wadd)
{
    int t2 = blockIdx.x * 256 + threadIdx.x;   // < 22*4096
    int f = t2 >> 12, rr = t2 & (RR - 1);
    float acc = 0.f;
#pragma unroll
    for (int c = 0; c < NCHUNK; c++)
        acc += Smig[(c * 22 + f) * RR + rr];
    Wadd[rr * 24 + f] = acc;
}

// ---------------- kernel 5: finalize population (wave/region) + region2-from-T ----------------
__global__ __launch_bounds__(256) void k_fin(
    const float* __restrict__ Wpa, const float* __restrict__ Wadd,
    const float* __restrict__ cw, const float* __restrict__ pw,
    const float* __restrict__ cbase, const float* __restrict__ lbase,
    const float* __restrict__ T,
    const float* __restrict__ Wdfrac, const float* __restrict__ Wbsurv,
    const float* __restrict__ patp, const float* __restrict__ padp,
    const float* __restrict__ pamp,
    float4* __restrict__ P4, float2* __restrict__ P2,
    float* __restrict__ O)
{
    int blk = blockIdx.x;
    if (blk < 1024) {
        int wid = threadIdx.x >> 6, lane = threadIdx.x & 63;
        int r = blk * 4 + wid;
        int a0 = lane * 2, a1 = a0 + 1;
        bool v0 = (a0 < AA), v1 = (a1 < AA);

        float va = 0.f, vb = 0.f;
        if (lane < 51) {
            float2 pp = *(const float2*)&Wpa[r * PAD_W + a0];
            va = pp.x; vb = pp.y;
        }
        if (a0 >= 18 && a0 < 40) {
            float2 ad = *(const float2*)&Wadd[r * 24 + (a0 - 18)];
            va += ad.x; vb += ad.y;
        }
        va = v0 ? fmaxf(va, 0.0f) : 0.f;
        vb = v1 ? fmaxf(vb, 0.0f) : 0.f;
        if (v0) O[OUT_POP + r * AA + a0] = va;
        if (v1) O[OUT_POP + r * AA + a1] = vb;

        float cw0 = v0 ? cw[a0] : 0.f, cw1 = v1 ? cw[a1] : 0.f;
        float pw0 = v0 ? pw[a0] : 0.f, pw1 = v1 ? pw[a1] : 0.f;

        float psum  = wred(va + vb);
        float cdot  = wred(va * cw0 + vb * cw1);
        float ldot  = wred(va * pw0 + vb * pw1);
        float young = wred(((a0 < 15) ? va : 0.f) + ((a1 < 15) ? vb : 0.f));
        float work  = wred(((a0 >= 15 && a0 < 65) ? va : 0.f) + ((a1 >= 15 && a1 < 65) ? vb : 0.f));
        float old   = wred(((a0 >= 65) ? va : 0.f) + ((a1 >= 65) ? vb : 0.f));

        if (lane == 0) {
            O[OUT_POPN + r] = fmaxf(psum, 0.0f);
            O[OUT_CONS + r] = clampf(cdot / (cbase[r] + EPS), 0.25f, 4.0f);
            O[OUT_LAB + r]  = clampf(ldot / (lbase[r] + EPS), 0.2f, 1.2f);
            O[OUT_PSR + r]  = work / (old + EPS);
            O[OUT_DEP + r]  = (young + old) / (work + EPS);
        }
    } else {
        int r = (blk - 1024) * 256 + threadIdx.x;
        if (r >= RR) return;
        float sums[5];
#pragma unroll
        for (int s = 0; s < 5; s++) {
            float acc = 0.f;
#pragma unroll
            for (int c = 0; c < CH; c++)
                acc += T[(s * CH + c) * RR + r];
            sums[s] = acc;
        }
        float dfi = Wdfrac[r];
        float ra = sums[0] * dfi;
        float rd = sums[1] * dfi;
        float rm = sums[2] * dfi;
        O[OUT_PATP + r] = patp[r] - ra * 0.2f;
        O[OUT_PADP + r] = padp[r] - rd * 0.2f;
        O[OUT_PAMP + r] = pamp[r] - rm * 0.2f;
        P4[r] = make_float4(1.0f - dfi, 1.0f / (sums[3] + EPS), ra * 0.8f, rd * 0.8f);
        P2[r] = make_float2(rm * 0.8f, Wbsurv[r] / fmaxf(sums[4], 1.0f));
    }
}

// ---------------- kernel 6: agent apply, float4 ----------------
__global__ __launch_bounds__(256) void k_apply(
    const int* __restrict__ reg, const float* __restrict__ greed,
    const float* __restrict__ atp, const float* __restrict__ adp,
    const float* __restrict__ amp,
    const float4* __restrict__ P4, const float2* __restrict__ P2,
    float* __restrict__ O)
{
    int q = blockIdx.x * 256 + threadIdx.x;
    if (q >= NAG / 4) return;
    int4 rr = ((const int4*)reg)[q];
    float4 g = ((const float4*)greed)[q];
    float4 a = ((const float4*)atp)[q];
    float4 d = ((const float4*)adp)[q];
    float4 m = ((const float4*)amp)[q];
    float4 oa, od, om;
#define ONE(c) { float4 t4 = P4[rr.c]; float2 t2 = P2[rr.c]; \
    float wn = (g.c + 1e-9f) * t4.y; \
    oa.c = a.c * t4.x + wn * t4.z + t2.y; \
    od.c = d.c * t4.x + wn * t4.w; \
    om.c = m.c * t4.x + wn * t2.x; }
    ONE(x) ONE(y) ONE(z) ONE(w)
#undef ONE
    ((float4*)(O + OUT_ATP))[q] = oa;
    ((float4*)(O + OUT_ADP))[q] = od;
    ((float4*)(O + OUT_AMP))[q] = om;
}

extern "C" void kernel_launch(void* const* d_in, const int* in_sizes, int n_in,
                              void* d_out, int out_size, void* d_ws, size_t ws_size,
                              hipStream_t stream) {
    const float* aec       = (const float*)d_in[0];
    const float* gdp_pc    = (const float*)d_in[1];
    const float* gdp_ema   = (const float*)d_in[2];
    const float* gdp_base  = (const float*)d_in[3];
    const float* dev_in    = (const float*)d_in[4];
    const float* sink_use  = (const float*)d_in[5];
    const float* sink_cap  = (const float*)d_in[6];
    const float* haz_base  = (const float*)d_in[7];
    const float* pop_age   = (const float*)d_in[8];
    const float* population= (const float*)d_in[9];
    const float* aging     = (const float*)d_in[10];
    const float* asfr      = (const float*)d_in[11];
    const float* distance  = (const float*)d_in[12];
    const float* cw        = (const float*)d_in[13];
    const float* pw        = (const float*)d_in[14];
    const float* cbase     = (const float*)d_in[15];
    const float* lbase     = (const float*)d_in[16];
    const float* greed     = (const float*)d_in[17];
    const float* eATP      = (const float*)d_in[18];
    const float* eADP      = (const float*)d_in[19];
    const float* eAMP      = (const float*)d_in[20];
    const float* patp      = (const float*)d_in[21];
    const float* padp      = (const float*)d_in[22];
    const float* pamp      = (const float*)d_in[23];
    const int*   nbr       = (const int*)d_in[24];
    const int*   reg       = (const int*)d_in[25];

    float* O = (float*)d_out;

    // -------- workspace layout (f32 units) --------
    float* W = (float*)d_ws;
    float* Wpa    = W;                       // RR*104
    float* Wdfrac = Wpa    + RR * PAD_W;
    float* Wbsurv = Wdfrac + RR;
    float* Wattr  = Wbsurv + RR;
    float* Wdsum  = Wattr  + RR;
    float* Wgdist = Wdsum  + RR;             // RR*32
    float* Wash   = Wgdist + RR * KK;        // RR*22
    float* Wmove  = Wash   + RR * 22;        // RR*32
    float* P4f    = Wmove  + RR * KK;        // RR*4
    float* P2f    = P4f    + RR * 4;         // RR*2
    float* Wadd   = P2f    + RR * 2;         // RR*24
    float* T      = Wadd   + RR * 24;        // 5*CH*RR
    float* Smig   = T      + 5 * CH * RR;    // NCHUNK*22*RR
    unsigned long long* S = (unsigned long long*)(Smig + (size_t)NCHUNK * 22 * RR); // NB*RR u64

    k_r1hist<<<1024 + NB, 256, 0, stream>>>(
        aec, gdp_pc, gdp_ema, gdp_base, dev_in, sink_use, sink_cap, haz_base,
        pop_age, population, aging, asfr, distance, nbr,
        Wpa, Wdfrac, Wbsurv, Wattr, Wgdist, Wdsum,
        reg, greed, eATP, eADP, eAMP, S, O);

    k_migrate_a<<<RR / 4, 256, 0, stream>>>(nbr, Wattr, Wgdist, Wdsum, Wpa, Wash, Wmove);

    k_mbdec<<<NMIG + 128, 512, 0, stream>>>(nbr, Wash, Wmove, Smig, S, T);

    k_fold<<<(22 * RR) / 256, 256, 0, stream>>>(Smig, Wadd);

    k_fin<<<1024 + RR / 256, 256, 0, stream>>>(
        Wpa, Wadd, cw, pw, cbase, lbase, T, Wdfrac, Wbsurv,
        patp, padp, pamp, (float4*)P4f, (float2*)P2f, O);

    k_apply<<<(NAG / 4 + 255) / 256, 256, 0, stream>>>(
        reg, greed, eATP, eADP, eAMP, (const float4*)P4f, (const float2*)P2f, O);
}

// Round 13
// 89.587 us; speedup vs baseline: 1.5213x; 1.0359x over previous
//
#include <hip/hip_runtime.h>

#define RR 4096
#define AA 101
#define PAD_W 104
#define KK 32
#define NAG 4000000

#define NCHUNK 32
#define DR 512
#define NRANGE 8
#define EPB (RR * KK / NCHUNK)   // 4096 edges per chunk
#define NB 512                   // hist blocks
#define NMIG (NRANGE * NCHUNK)   // 256 migrate blocks
#define CH 16                    // S-reduce chunks

static constexpr float EPS  = 1e-9f;
static constexpr float DT   = 1.0f / 365.0f;
static constexpr float FRAC_MOVE = 0.02f / 365.0f;

static constexpr float SC2   = 4.0f;             // wallet quantum 0.25
static constexpr float INV2  = 0.25f;
static constexpr float SC9   = 512.0f;           // greed quantum 2^-9
static constexpr float INV9  = 1.0f / 512.0f;
static constexpr float SC18  = 262144.0f;        // 2^18 (migrate)
static constexpr float INV18 = 1.0f / 262144.0f;

// ---------------- d_out offsets (f32 elements, return order) ----------------
#define OUT_POP   0
#define OUT_POPN  413696
#define OUT_GDP   417792
#define OUT_DEV   421888
#define OUT_H     425984
#define OUT_CONS  430080
#define OUT_LAB   434176
#define OUT_PSR   438272
#define OUT_DEP   442368
#define OUT_ATP   446464
#define OUT_ADP   4446464
#define OUT_AMP   8446464
#define OUT_PATP  12446464
#define OUT_PADP  12450560
#define OUT_PAMP  12454656

static __device__ __forceinline__ float clampf(float x, float lo, float hi) {
    return fminf(fmaxf(x, lo), hi);
}
static __device__ __forceinline__ float wred(float x) {
#pragma unroll
    for (int m = 32; m; m >>= 1) x += __shfl_xor(x, m);
    return x;
}

// ---------------- kernel 1: FUSED region1 (blocks [0,256), 16 regions each)
//                  + agent hist (blocks [256,256+NB), 1024 thr, 2 blocks/CU = 100% occ) ----------------
__global__ __launch_bounds__(1024) void k_r1hist(
    const float* __restrict__ aec, const float* __restrict__ gdp_pc,
    const float* __restrict__ gdp_ema_in, const float* __restrict__ gdp_base,
    const float* __restrict__ dev_in, const float* __restrict__ sink_use,
    const float* __restrict__ sink_cap, const float* __restrict__ haz_base,
    const float* __restrict__ pop_age, const float* __restrict__ population,
    const float* __restrict__ aging, const float* __restrict__ asfr,
    const float* __restrict__ distance, const int* __restrict__ nbr,
    float* __restrict__ Wpa, float* __restrict__ Wdfrac, float* __restrict__ Wbsurv,
    float* __restrict__ Wattr, float* __restrict__ Wgdist, float* __restrict__ Wdsum,
    const int* __restrict__ reg, const float* __restrict__ greed,
    const float* __restrict__ atp, const float* __restrict__ adp,
    const float* __restrict__ amp, unsigned long long* __restrict__ S,
    float* __restrict__ O)
{
    __shared__ unsigned long long h[RR];      // 32 KiB (hist role only)
    int blk = blockIdx.x;

    if (blk < 256) {
        // ---- region1 role: 16 regions per block, wave per region ----
        int wid = threadIdx.x >> 6, lane = threadIdx.x & 63;
        int r = blk * 16 + wid;

        float aec_norm = clampf(aec[r], 0.0f, 1.0f);
        float gprev = gdp_ema_in[r];
        float gema  = gprev * 0.9f + 0.1f * gdp_pc[r];
        float base  = gdp_base[r];
        float g_ratio = logf(fmaxf(gema / (base + EPS), 1e-6f));
        float g_term  = clampf(0.5f + 0.5f * tanhf(0.5f * g_ratio), 0.0f, 1.0f);
        float util = clampf(sink_use[r] / (sink_cap[r] + EPS), 0.0f, 1.0f);
        float H = clampf(0.5f * aec_norm + 0.4f * g_term + 0.1f * (1.0f - util), 0.0f, 1.0f);
        float dev_proxy = clampf(0.5f + 0.5f * tanhf(0.3f * g_ratio), 0.0f, 1.0f);
        float dev = dev_in[r] * 0.99f + 0.01f * dev_proxy;

        float m_neon  = expf(-2.0f * H);
        float m_child = expf(-1.5f * H);
        float m_adult = expf(-1.0f * H);
        float hazmul = 1.0f + 0.5f * util;

        int a0 = lane * 2, a1 = a0 + 1;
        bool v0 = (a0 < AA), v1 = (a1 < AA);

        float p0 = 0.f, p1 = 0.f, hz0 = 0.f, hz1 = 0.f;
        if (v0) {
            p0 = pop_age[r * AA + a0];
            float mult = (a0 == 0) ? m_neon : ((a0 < 15) ? m_child : m_adult);
            hz0 = clampf(haz_base[a0] * mult * hazmul, 0.0f, 5.0f);
        }
        if (v1) {
            p1 = pop_age[r * AA + a1];
            float mult = (a1 < 15) ? m_child : m_adult;
            hz1 = clampf(haz_base[a1] * mult * hazmul, 0.0f, 5.0f);
        }
        float s0 = v0 ? p0 * expf(-hz0 * DT) : 0.f;
        float s1 = v1 ? p1 * expf(-hz1 * DT) : 0.f;
        float sp = __shfl_up(s1, 1);   // s[a0-1]

        float Md0 = 0.f, Md1 = 0.f, Ms0 = 0.f, Ms1 = 0.f;
        if (v0) { Md0 = aging[a0 * AA + a0]; if (a0 > 0) Ms0 = aging[(a0 - 1) * AA + a0]; }
        if (v1) { Md1 = aging[a1 * AA + a1]; Ms1 = aging[(a1 - 1) * AA + a1]; }

        float pa0 = v0 ? ((a0 == 0) ? s0 * Md0 : s0 * Md0 + sp * Ms0) : 0.f;
        float pa1 = v1 ? (s1 * Md1 + s0 * Ms1) : 0.f;

        if (v0 && a0 > 0) Wpa[r * PAD_W + a0] = pa0;
        if (v1)           Wpa[r * PAD_W + a1] = pa1;

        float pop_sum  = wred(p0 + p1);
        float surv_sum = wred(s0 + s1);
        float haz05 = wred(((v0 && a0 < 5) ? hz0 : 0.f) + ((v1 && a1 < 5) ? hz1 : 0.f));
        float bs0 = (a0 >= 15 && a0 < 50) ? 0.5f * pa0 * asfr[a0 - 15] : 0.f;
        float bs1 = (a1 >= 15 && a1 < 50) ? 0.5f * pa1 * asfr[a1 - 15] : 0.f;
        float b_sum = wred(bs0 + bs1);

        float dc = 0.f;
        if (lane < KK) {
            int idx = nbr[r * KK + lane];
            float d = distance[(size_t)r * RR + idx];
            Wgdist[r * KK + lane] = d;
            dc = d;
        }
        float dsum = wred(dc);

        if (lane == 0) {
            O[OUT_GDP + r] = gema;
            O[OUT_DEV + r] = dev;
            O[OUT_H + r]   = H;

            float deaths = fmaxf(pop_sum - surv_sum, 0.0f);
            Wdfrac[r] = clampf(deaths / (population[r] + EPS), 0.0f, 0.99f);

            float surv_u5 = expf(-haz05);
            float F_dev = clampf(expf(-dev), 0.5f, 1.5f);
            float F_rep = clampf(0.995f / fmaxf(surv_u5, 0.001f), 0.5f, 1.8f);
            float g_growth = logf(fmaxf(gema + EPS, 1e-6f)) - logf(fmaxf(gprev + EPS, 1e-6f));
            float F_cyc = clampf(expf(-5.0f * fmaxf(-g_growth, 0.0f)), 0.6f, 1.2f);
            float F_total = clampf(F_dev * F_rep * F_cyc, 0.4f, 1.8f);
            float births = fmaxf(b_sum * F_total * DT, 0.0f);
            float bsurv = births * expf(-hz0 * DT);       // hz0 on lane0 = haz[0]
            Wbsurv[r] = bsurv;
            Wpa[r * PAD_W + 0] = pa0 + bsurv;             // lane0 pa0 = pa(age 0)

            Wattr[r] = 0.6f * (gdp_pc[r] / (base + EPS)) + 0.4f * (0.5f + 0.5f * aec_norm);
            Wdsum[r] = dsum;
        }
    } else {
        // ---- hist role: ONE u64 atomic per agent, 1024 threads, full occupancy ----
        int b = blk - 256;
        for (int i = threadIdx.x; i < RR; i += 1024) h[i] = 0ull;
        __syncthreads();

        const int4*   reg4 = (const int4*)reg;
        const float4* g4 = (const float4*)greed;
        const float4* a4 = (const float4*)atp;
        const float4* d4 = (const float4*)adp;
        const float4* m4 = (const float4*)amp;
        const int NQ = NAG / 4;
        const int STRIDE = NB * 1024;

        for (int q = b * 1024 + threadIdx.x; q < NQ; q += STRIDE) {
            int4 rr = reg4[q];
            float4 gv = g4[q], av = a4[q], dv = d4[q], mv = m4[q];
#define DO1(RX, GX, AX, DX, MX) { \
            unsigned long long ai = __float2uint_rn((AX) * SC2); \
            unsigned long long di = __float2uint_rn((DX) * SC2); \
            unsigned long long mi = __float2uint_rn((MX) * SC2); \
            unsigned long long gi = __float2uint_rn(((GX) + 1e-9f) * SC9); \
            atomicAdd(&h[RX], ai | (di << 14) | (mi << 28) | (gi << 42) | (1ull << 56)); }
            DO1(rr.x, gv.x, av.x, dv.x, mv.x)
            DO1(rr.y, gv.y, av.y, dv.y, mv.y)
            DO1(rr.z, gv.z, av.z, dv.z, mv.z)
            DO1(rr.w, gv.w, av.w, dv.w, mv.w)
#undef DO1
        }
        __syncthreads();

        for (int i = threadIdx.x; i < RR; i += 1024)
            S[(size_t)b * RR + i] = h[i];
    }
}

// ---------------- kernel 2: migration weights + outflow (means inlined) ----------------
__global__ __launch_bounds__(256) void k_migrate_a(
    const int* __restrict__ nbr, const float* __restrict__ Wattr,
    const float* __restrict__ Wgdist, const float* __restrict__ Wdsum,
    float* __restrict__ Wpa, float* __restrict__ Wash, float* __restrict__ Wmove)
{
    __shared__ float sred[8];
    int t = threadIdx.x;
    {
        float a = 0.f, d = 0.f;
        for (int i = t; i < RR; i += 256) { a += Wattr[i]; d += Wdsum[i]; }
        a = wred(a); d = wred(d);
        int w0 = t >> 6;
        if ((t & 63) == 0) { sred[w0] = a; sred[4 + w0] = d; }
    }
    __syncthreads();
    float asum = sred[0] + sred[1] + sred[2] + sred[3];
    float dall = sred[4] + sred[5] + sred[6] + sred[7];
    float inv_am = 1.0f / (asum / (float)RR + EPS);
    float inv_dm = 1.0f / (dall / (float)(RR * KK) + EPS);

    int wid = t >> 6, lane = t & 63;
    int r = blockIdx.x * 4 + wid;

    float mob = 0.f;
    if (lane < 22) mob = Wpa[r * PAD_W + 18 + lane];
    float msum = wred(lane < 22 ? mob : 0.f);

    float w = 0.f;
    if (lane < KK) {
        int idx = nbr[r * KK + lane];
        float an = Wattr[idx] * inv_am;
        float cost = 1.0f + Wgdist[r * KK + lane] * inv_dm;
        w = fmaxf(an / cost, 0.0f);
    }
    float wsum = wred(lane < KK ? w : 0.f);

    float out_R = msum * FRAC_MOVE;
    float invw = 1.0f / (wsum + EPS);
    float move_sum = out_R * wsum * invw;
    float inv_ms = 1.0f / (msum + EPS);

    if (lane < 22) {
        float ash = mob * inv_ms;
        Wash[r * 22 + lane] = ash;
        Wpa[r * PAD_W + 18 + lane] = mob - ash * move_sum;
    }
    if (lane < KK) Wmove[r * KK + lane] = out_R * w * invw;
}

// ---------------- kernel 3: FUSED migrate_b (blocks [0,NMIG)) + S->T decode (blocks [NMIG,NMIG+128)) ----------------
__global__ __launch_bounds__(512) void k_mbdec(
    const int* __restrict__ nbr, const float* __restrict__ Wash,
    const float* __restrict__ Wmove, float* __restrict__ Smig,
    const unsigned long long* __restrict__ S, float* __restrict__ T)
{
    __shared__ unsigned long long h[11 * DR];   // 45056 B (migrate role only)
    int bid = blockIdx.x;

    if (bid < NMIG) {
        int range = bid & (NRANGE - 1);
        int chunk = bid >> 3;
        int d0 = range * DR;

        for (int i = threadIdx.x; i < 11 * DR; i += 512) h[i] = 0ull;
        __syncthreads();

        int tend = (chunk + 1) * EPB;
        for (int t = chunk * EPB + threadIdx.x; t < tend; t += 512) {
            int idx = nbr[t];
            if (idx >= d0 && idx < d0 + DR) {
                int rsrc = t >> 5;
                float mv = Wmove[t];
                const float* ash = &Wash[rsrc * 22];
                int dl = idx - d0;
#pragma unroll
                for (int f = 0; f < 11; f++) {
                    unsigned long long lo = __float2uint_rn(ash[2 * f] * mv * SC18);
                    unsigned long long hi = __float2uint_rn(ash[2 * f + 1] * mv * SC18);
                    atomicAdd(&h[f * DR + dl], lo | (hi << 32));
                }
            }
        }
        __syncthreads();

        for (int i = threadIdx.x; i < 11 * DR; i += 512) {
            int f = i / DR, d = i - f * DR;
            unsigned long long v = h[i];
            Smig[(chunk * 22 + 2 * f) * RR + d0 + d]     = (float)(unsigned int)v * INV18;
            Smig[(chunk * 22 + 2 * f + 1) * RR + d0 + d] = (float)(v >> 32) * INV18;
        }
    } else {
        int tid = (bid - NMIG) * 512 + threadIdx.x;   // < 16*4096
        int r = tid & (RR - 1);
        int c = tid >> 12;                            // chunk in [0,16)
        const int bpc = NB / CH;                      // 32
        float sa = 0.f, sd = 0.f, sm = 0.f, sg = 0.f, sc = 0.f;
        for (int b = c * bpc; b < (c + 1) * bpc; b++) {
            unsigned long long p = S[(size_t)b * RR + r];
            sa += (float)(unsigned int)(p & 0x3FFFull);
            sd += (float)(unsigned int)((p >> 14) & 0x3FFFull);
            sm += (float)(unsigned int)((p >> 28) & 0x3FFFull);
            sg += (float)(unsigned int)((p >> 42) & 0x3FFFull);
            sc += (float)(unsigned int)(p >> 56);
        }
        T[(0 * CH + c) * RR + r] = sa * INV2;
        T[(1 * CH + c) * RR + r] = sd * INV2;
        T[(2 * CH + c) * RR + r] = sm * INV2;
        T[(3 * CH + c) * RR + r] = sg * INV9;
        T[(4 * CH + c) * RR + r] = sc;
    }
}

// ---------------- kernel 4: fold Smig -> Wadd (coalesced) ----------------
__global__ __launch_bounds__(256) void k_fold(
    const float* __restrict__ Smig, float* __restrict__ Wadd)
{
    int t2 = blockIdx.x * 256 + threadIdx.x;   // < 22*4096
    int f = t2 >> 12, rr = t2 & (RR - 1);
    float acc = 0.f;
#pragma unroll
    for (int c = 0; c < NCHUNK; c++)
        acc += Smig[(c * 22 + f) * RR + rr];
    Wadd[rr * 24 + f] = acc;
}

// ---------------- kernel 5: finalize population (wave/region) + region2-from-T ----------------
__global__ __launch_bounds__(256) void k_fin(
    const float* __restrict__ Wpa, const float* __restrict__ Wadd,
    const float* __restrict__ cw, const float* __restrict__ pw,
    const float* __restrict__ cbase, const float* __restrict__ lbase,
    const float* __restrict__ T,
    const float* __restrict__ Wdfrac, const float* __restrict__ Wbsurv,
    const float* __restrict__ patp, const float* __restrict__ padp,
    const float* __restrict__ pamp,
    float4* __restrict__ P4, float2* __restrict__ P2,
    float* __restrict__ O)
{
    int blk = blockIdx.x;
    if (blk < 1024) {
        int wid = threadIdx.x >> 6, lane = threadIdx.x & 63;
        int r = blk * 4 + wid;
        int a0 = lane * 2, a1 = a0 + 1;
        bool v0 = (a0 < AA), v1 = (a1 < AA);

        float va = 0.f, vb = 0.f;
        if (lane < 51) {
            float2 pp = *(const float2*)&Wpa[r * PAD_W + a0];
            va = pp.x; vb = pp.y;
        }
        if (a0 >= 18 && a0 < 40) {
            float2 ad = *(const float2*)&Wadd[r * 24 + (a0 - 18)];
            va += ad.x; vb += ad.y;
        }
        va = v0 ? fmaxf(va, 0.0f) : 0.f;
        vb = v1 ? fmaxf(vb, 0.0f) : 0.f;
        if (v0) O[OUT_POP + r * AA + a0] = va;
        if (v1) O[OUT_POP + r * AA + a1] = vb;

        float cw0 = v0 ? cw[a0] : 0.f, cw1 = v1 ? cw[a1] : 0.f;
        float pw0 = v0 ? pw[a0] : 0.f, pw1 = v1 ? pw[a1] : 0.f;

        float psum  = wred(va + vb);
        float cdot  = wred(va * cw0 + vb * cw1);
        float ldot  = wred(va * pw0 + vb * pw1);
        float young = wred(((a0 < 15) ? va : 0.f) + ((a1 < 15) ? vb : 0.f));
        float work  = wred(((a0 >= 15 && a0 < 65) ? va : 0.f) + ((a1 >= 15 && a1 < 65) ? vb : 0.f));
        float old   = wred(((a0 >= 65) ? va : 0.f) + ((a1 >= 65) ? vb : 0.f));

        if (lane == 0) {
            O[OUT_POPN + r] = fmaxf(psum, 0.0f);
            O[OUT_CONS + r] = clampf(cdot / (cbase[r] + EPS), 0.25f, 4.0f);
            O[OUT_LAB + r]  = clampf(ldot / (lbase[r] + EPS), 0.2f, 1.2f);
            O[OUT_PSR + r]  = work / (old + EPS);
            O[OUT_DEP + r]  = (young + old) / (work + EPS);
        }
    } else {
        int r = (blk - 1024) * 256 + threadIdx.x;
        if (r >= RR) return;
        float sums[5];
#pragma unroll
        for (int s = 0; s < 5; s++) {
            float acc = 0.f;
#pragma unroll
            for (int c = 0; c < CH; c++)
                acc += T[(s * CH + c) * RR + r];
            sums[s] = acc;
        }
        float dfi = Wdfrac[r];
        float ra = sums[0] * dfi;
        float rd = sums[1] * dfi;
        float rm = sums[2] * dfi;
        O[OUT_PATP + r] = patp[r] - ra * 0.2f;
        O[OUT_PADP + r] = padp[r] - rd * 0.2f;
        O[OUT_PAMP + r] = pamp[r] - rm * 0.2f;
        P4[r] = make_float4(1.0f - dfi, 1.0f / (sums[3] + EPS), ra * 0.8f, rd * 0.8f);
        P2[r] = make_float2(rm * 0.8f, Wbsurv[r] / fmaxf(sums[4], 1.0f));
    }
}

// ---------------- kernel 6: agent apply, float4 ----------------
__global__ __launch_bounds__(256) void k_apply(
    const int* __restrict__ reg, const float* __restrict__ greed,
    const float* __restrict__ atp, const float* __restrict__ adp,
    const float* __restrict__ amp,
    const float4* __restrict__ P4, const float2* __restrict__ P2,
    float* __restrict__ O)
{
    int q = blockIdx.x * 256 + threadIdx.x;
    if (q >= NAG / 4) return;
    int4 rr = ((const int4*)reg)[q];
    float4 g = ((const float4*)greed)[q];
    float4 a = ((const float4*)atp)[q];
    float4 d = ((const float4*)adp)[q];
    float4 m = ((const float4*)amp)[q];
    float4 oa, od, om;
#define ONE(c) { float4 t4 = P4[rr.c]; float2 t2 = P2[rr.c]; \
    float wn = (g.c + 1e-9f) * t4.y; \
    oa.c = a.c * t4.x + wn * t4.z + t2.y; \
    od.c = d.c * t4.x + wn * t4.w; \
    om.c = m.c * t4.x + wn * t2.x; }
    ONE(x) ONE(y) ONE(z) ONE(w)
#undef ONE
    ((float4*)(O + OUT_ATP))[q] = oa;
    ((float4*)(O + OUT_ADP))[q] = od;
    ((float4*)(O + OUT_AMP))[q] = om;
}

extern "C" void kernel_launch(void* const* d_in, const int* in_sizes, int n_in,
                              void* d_out, int out_size, void* d_ws, size_t ws_size,
                              hipStream_t stream) {
    const float* aec       = (const float*)d_in[0];
    const float* gdp_pc    = (const float*)d_in[1];
    const float* gdp_ema   = (const float*)d_in[2];
    const float* gdp_base  = (const float*)d_in[3];
    const float* dev_in    = (const float*)d_in[4];
    const float* sink_use  = (const float*)d_in[5];
    const float* sink_cap  = (const float*)d_in[6];
    const float* haz_base  = (const float*)d_in[7];
    const float* pop_age   = (const float*)d_in[8];
    const float* population= (const float*)d_in[9];
    const float* aging     = (const float*)d_in[10];
    const float* asfr      = (const float*)d_in[11];
    const float* distance  = (const float*)d_in[12];
    const float* cw        = (const float*)d_in[13];
    const float* pw        = (const float*)d_in[14];
    const float* cbase     = (const float*)d_in[15];
    const float* lbase     = (const float*)d_in[16];
    const float* greed     = (const float*)d_in[17];
    const float* eATP      = (const float*)d_in[18];
    const float* eADP      = (const float*)d_in[19];
    const float* eAMP      = (const float*)d_in[20];
    const float* patp      = (const float*)d_in[21];
    const float* padp      = (const float*)d_in[22];
    const float* pamp      = (const float*)d_in[23];
    const int*   nbr       = (const int*)d_in[24];
    const int*   reg       = (const int*)d_in[25];

    float* O = (float*)d_out;

    // -------- workspace layout (f32 units) --------
    float* W = (float*)d_ws;
    float* Wpa    = W;                       // RR*104
    float* Wdfrac = Wpa    + RR * PAD_W;
    float* Wbsurv = Wdfrac + RR;
    float* Wattr  = Wbsurv + RR;
    float* Wdsum  = Wattr  + RR;
    float* Wgdist = Wdsum  + RR;             // RR*32
    float* Wash   = Wgdist + RR * KK;        // RR*22
    float* Wmove  = Wash   + RR * 22;        // RR*32
    float* P4f    = Wmove  + RR * KK;        // RR*4
    float* P2f    = P4f    + RR * 4;         // RR*2
    float* Wadd   = P2f    + RR * 2;         // RR*24
    float* T      = Wadd   + RR * 24;        // 5*CH*RR
    float* Smig   = T      + 5 * CH * RR;    // NCHUNK*22*RR
    unsigned long long* S = (unsigned long long*)(Smig + (size_t)NCHUNK * 22 * RR); // NB*RR u64

    k_r1hist<<<256 + NB, 1024, 0, stream>>>(
        aec, gdp_pc, gdp_ema, gdp_base, dev_in, sink_use, sink_cap, haz_base,
        pop_age, population, aging, asfr, distance, nbr,
        Wpa, Wdfrac, Wbsurv, Wattr, Wgdist, Wdsum,
        reg, greed, eATP, eADP, eAMP, S, O);

    k_migrate_a<<<RR / 4, 256, 0, stream>>>(nbr, Wattr, Wgdist, Wdsum, Wpa, Wash, Wmove);

    k_mbdec<<<NMIG + 128, 512, 0, stream>>>(nbr, Wash, Wmove, Smig, S, T);

    k_fold<<<(22 * RR) / 256, 256, 0, stream>>>(Smig, Wadd);

    k_fin<<<1024 + RR / 256, 256, 0, stream>>>(
        Wpa, Wadd, cw, pw, cbase, lbase, T, Wdfrac, Wbsurv,
        patp, padp, pamp, (float4*)P4f, (float2*)P2f, O);

    k_apply<<<(NAG / 4 + 255) / 256, 256, 0, stream>>>(
        reg, greed, eATP, eADP, eAMP, (const float4*)P4f, (const float2*)P2f, O);
}